// Round 3
// baseline (1114.427 us; speedup 1.0000x reference)
//
#include <hip/hip_runtime.h>

typedef unsigned short ushort_t;
typedef unsigned int u32;
typedef __attribute__((ext_vector_type(4))) float f32x4;
typedef __attribute__((ext_vector_type(8))) short bf16x8;

// Problem constants
#define T_DIM 8192
#define D_IN 1024
#define D_INTER 512
#define N_ELEM (T_DIM * D_INTER)  // 4194304

// ---------- helpers ----------
__device__ __forceinline__ unsigned short f2b(float f) {
  union { float f; u32 u; } v; v.f = f;
  u32 u = v.u;
  u32 r = (u + 0x7fffu + ((u >> 16) & 1u)) >> 16;
  return (unsigned short)r;
}

__device__ __forceinline__ void g2l16(const void* g, void* l) {
  __builtin_amdgcn_global_load_lds((const __attribute__((address_space(1))) u32*)g,
                                   (__attribute__((address_space(3))) u32*)l, 16, 0, 0);
}

// ---------- kernel 1: casts ----------
// segments (float4 units): x 2097152 | wq 131072 | wk 131072 | wv 131072 | wr 65536
__global__ void prep_kernel(const float4* __restrict__ x,
                            const float4* __restrict__ wq, const float4* __restrict__ wk,
                            const float4* __restrict__ wv, const float4* __restrict__ wr,
                            ushort4* __restrict__ xb,
                            ushort4* __restrict__ wqb, ushort4* __restrict__ wkb,
                            ushort4* __restrict__ wvb, ushort4* __restrict__ wrb,
                            float* __restrict__ stats) {
  const int gid = blockIdx.x * 256 + threadIdx.x;
  if (gid == 0) { stats[0] = 0.f; stats[1] = 0.f; }
  const float4* src; ushort4* dst; int idx;
  if (gid < 2097152)      { src = x;  dst = xb;  idx = gid; }
  else if (gid < 2228224) { src = wq; dst = wqb; idx = gid - 2097152; }
  else if (gid < 2359296) { src = wk; dst = wkb; idx = gid - 2228224; }
  else if (gid < 2490368) { src = wv; dst = wvb; idx = gid - 2359296; }
  else                    { src = wr; dst = wrb; idx = gid - 2490368; }
  float4 v = src[idx];
  ushort4 o;
  o.x = f2b(v.x); o.y = f2b(v.y); o.z = f2b(v.z); o.w = f2b(v.w);
  dst[idx] = o;
}

// ---------- kernel 2: QKV projections  C = xb @ W^T + b ----------
// M=8192, K=1024, N=512, blockIdx.z in {0:Q,1:K,2:V}. 128x128 tiles, BK=32.
// Q,K outputs k-packed over inter (cell(kg,row)); V k-packed over T (cell(tg,col)).
__global__ void gemm_qkv(const ushort_t* __restrict__ xb,
                         const ushort_t* __restrict__ wqb, const ushort_t* __restrict__ wkb,
                         const ushort_t* __restrict__ wvb,
                         const float* __restrict__ bq, const float* __restrict__ bk,
                         const float* __restrict__ bv,
                         ushort_t* __restrict__ Qp, ushort_t* __restrict__ Kp,
                         ushort_t* __restrict__ Vp) {
  __shared__ ushort_t As[4 * 130 * 8];
  __shared__ ushort_t Bs[4 * 130 * 8];
  const int tid = threadIdx.x, wid = tid >> 6, lane = tid & 63;
  const int l15 = lane & 15, q4 = lane >> 4;
  const int m0 = blockIdx.x * 128, n0 = blockIdx.y * 128;
  const int z = blockIdx.z;
  const ushort_t* wb = (z == 0) ? wqb : (z == 1 ? wkb : wvb);
  const float* bias = (z == 0) ? bq : (z == 1 ? bk : bv);
  const int m0w = (wid >> 1) * 64, n0w = (wid & 1) * 64;

  f32x4 acc[4][4];
#pragma unroll
  for (int a = 0; a < 4; ++a)
#pragma unroll
    for (int b = 0; b < 4; ++b) acc[a][b] = f32x4{0.f, 0.f, 0.f, 0.f};

  for (int kt = 0; kt < 32; ++kt) {
#pragma unroll
    for (int j = 0; j < 4; ++j) {
      const int idx = wid * 4 + j;
      const int kg = (idx >> 1) & 3;
      const int half = idx & 1;
      if (idx < 8)
        g2l16(&xb[(size_t)(m0 + half * 64 + lane) * 1024 + kt * 32 + kg * 8],
              &As[(kg * 130 + half * 64) * 8]);
      else
        g2l16(&wb[(size_t)(n0 + half * 64 + lane) * 1024 + kt * 32 + kg * 8],
              &Bs[(kg * 130 + half * 64) * 8]);
    }
    __syncthreads();
    bf16x8 af[4], bfr[4];
#pragma unroll
    for (int t = 0; t < 4; ++t) {
      af[t]  = *(const bf16x8*)&As[(q4 * 130 + m0w + t * 16 + l15) * 8];
      bfr[t] = *(const bf16x8*)&Bs[(q4 * 130 + n0w + t * 16 + l15) * 8];
    }
#pragma unroll
    for (int mt = 0; mt < 4; ++mt)
#pragma unroll
      for (int nt = 0; nt < 4; ++nt)
        acc[mt][nt] = __builtin_amdgcn_mfma_f32_16x16x32_bf16(af[mt], bfr[nt], acc[mt][nt], 0, 0, 0);
    __syncthreads();
  }

#pragma unroll
  for (int nt = 0; nt < 4; ++nt) {
    const int gcol = n0 + n0w + nt * 16 + l15;
    const float bb = bias[gcol];
#pragma unroll
    for (int mt = 0; mt < 4; ++mt)
#pragma unroll
      for (int i = 0; i < 4; ++i) {
        const int grow = m0 + m0w + mt * 16 + q4 * 4 + i;
        const unsigned short v = f2b(acc[mt][nt][i] + bb);
        if (z == 2)
          Vp[((size_t)(grow >> 3) * 512 + gcol) * 8 + (grow & 7)] = v;   // k = T rows
        else if (z == 1)
          Kp[((size_t)(gcol >> 3) * 8192 + grow) * 8 + (gcol & 7)] = v;  // k = inter
        else
          Qp[((size_t)(gcol >> 3) * 8192 + grow) * 8 + (gcol & 7)] = v;
      }
  }
}

// ---------- kernel 3a: P = dg o (Q K^T) -> bf16, row-major [8192 x 8192] ----------
// M=N=8192, K=512. Grid (64,64), 256 threads. m97 structure; dg applied in epilogue.
__global__ void gemm_s(const ushort_t* __restrict__ Qp, const ushort_t* __restrict__ Kp,
                       const float* __restrict__ dg, ushort_t* __restrict__ P) {
  __shared__ ushort_t As[4 * 130 * 8];
  __shared__ ushort_t Bs[4 * 130 * 8];
  const int tid = threadIdx.x, wid = tid >> 6, lane = tid & 63;
  const int l15 = lane & 15, q4 = lane >> 4;
  const int m0 = blockIdx.x * 128, n0 = blockIdx.y * 128;
  const int m0w = (wid >> 1) * 64, n0w = (wid & 1) * 64;

  f32x4 acc[4][4];
#pragma unroll
  for (int a = 0; a < 4; ++a)
#pragma unroll
    for (int b = 0; b < 4; ++b) acc[a][b] = f32x4{0.f, 0.f, 0.f, 0.f};

  for (int kt = 0; kt < 16; ++kt) {
#pragma unroll
    for (int j = 0; j < 4; ++j) {
      const int idx = wid * 4 + j;
      const int kg = (idx >> 1) & 3;
      const int half = idx & 1;
      if (idx < 8)
        g2l16(&Qp[((size_t)(kt * 4 + kg) * 8192 + m0 + half * 64 + lane) * 8],
              &As[(kg * 130 + half * 64) * 8]);
      else
        g2l16(&Kp[((size_t)(kt * 4 + kg) * 8192 + n0 + half * 64 + lane) * 8],
              &Bs[(kg * 130 + half * 64) * 8]);
    }
    __syncthreads();
    bf16x8 af[4], bfr[4];
#pragma unroll
    for (int t = 0; t < 4; ++t) {
      af[t]  = *(const bf16x8*)&As[(q4 * 130 + m0w + t * 16 + l15) * 8];
      bfr[t] = *(const bf16x8*)&Bs[(q4 * 130 + n0w + t * 16 + l15) * 8];
    }
#pragma unroll
    for (int mt = 0; mt < 4; ++mt)
#pragma unroll
      for (int nt = 0; nt < 4; ++nt)
        acc[mt][nt] = __builtin_amdgcn_mfma_f32_16x16x32_bf16(af[mt], bfr[nt], acc[mt][nt], 0, 0, 0);
    __syncthreads();
  }

  // epilogue: P[grow][gcol] = bf16( dg[grow][gcol] * acc )
#pragma unroll
  for (int mt = 0; mt < 4; ++mt)
#pragma unroll
    for (int i = 0; i < 4; ++i) {
      const size_t grow = (size_t)(m0 + m0w + mt * 16 + q4 * 4 + i);
#pragma unroll
      for (int nt = 0; nt < 4; ++nt) {
        const int gcol = n0 + n0w + nt * 16 + l15;
        const float g = dg[grow * 8192 + gcol];
        P[grow * 8192 + gcol] = f2b(acc[mt][nt][i] * g);
      }
    }
}

// ---------- kernel 3b: Hp[z] = P @ V  (split-K=4) ----------
// M=8192, N=512, K=8192 split into 4 chunks of 2048. Grid (64,4,4), 256 threads.
__global__ void gemm_pv(const ushort_t* __restrict__ P, const ushort_t* __restrict__ Vp,
                        float* __restrict__ Hp) {
  __shared__ ushort_t As[4 * 130 * 8];
  __shared__ ushort_t Bs[4 * 130 * 8];
  const int tid = threadIdx.x, wid = tid >> 6, lane = tid & 63;
  const int l15 = lane & 15, q4 = lane >> 4;
  const int m0 = blockIdx.x * 128, n0 = blockIdx.y * 128;
  const int kz = blockIdx.z;
  const int tg_base = kz * 256;  // k-chunk start in tg units (2048/8)
  const int m0w = (wid >> 1) * 64, n0w = (wid & 1) * 64;

  f32x4 acc[4][4];
#pragma unroll
  for (int a = 0; a < 4; ++a)
#pragma unroll
    for (int b = 0; b < 4; ++b) acc[a][b] = f32x4{0.f, 0.f, 0.f, 0.f};

  for (int kt = 0; kt < 64; ++kt) {
    const int kk = kz * 2048 + kt * 32;
#pragma unroll
    for (int j = 0; j < 4; ++j) {
      const int idx = wid * 4 + j;
      const int kg = (idx >> 1) & 3;
      const int half = idx & 1;
      if (idx < 8)
        g2l16(&P[(size_t)(m0 + half * 64 + lane) * 8192 + kk + kg * 8],
              &As[(kg * 130 + half * 64) * 8]);
      else
        g2l16(&Vp[((size_t)(tg_base + kt * 4 + kg) * 512 + n0 + half * 64 + lane) * 8],
              &Bs[(kg * 130 + half * 64) * 8]);
    }
    __syncthreads();
    bf16x8 af[4], bfr[4];
#pragma unroll
    for (int t = 0; t < 4; ++t) {
      af[t]  = *(const bf16x8*)&As[(q4 * 130 + m0w + t * 16 + l15) * 8];
      bfr[t] = *(const bf16x8*)&Bs[(q4 * 130 + n0w + t * 16 + l15) * 8];
    }
#pragma unroll
    for (int mt = 0; mt < 4; ++mt)
#pragma unroll
      for (int nt = 0; nt < 4; ++nt)
        acc[mt][nt] = __builtin_amdgcn_mfma_f32_16x16x32_bf16(af[mt], bfr[nt], acc[mt][nt], 0, 0, 0);
    __syncthreads();
  }

  float* hp = Hp + (size_t)kz * N_ELEM;
#pragma unroll
  for (int mt = 0; mt < 4; ++mt)
#pragma unroll
    for (int i = 0; i < 4; ++i) {
      const size_t grow = (size_t)(m0 + m0w + mt * 16 + q4 * 4 + i);
#pragma unroll
      for (int nt = 0; nt < 4; ++nt) {
        const int gcol = n0 + n0w + nt * 16 + l15;
        hp[grow * 512 + gcol] = acc[mt][nt][i];
      }
    }
}

// ---------- kernel 4: reduce split-K partials + global sum / sumsq ----------
__global__ void stats_kernel(const float4* __restrict__ Hp, float4* __restrict__ H,
                             float* __restrict__ stats) {
  const int gid = blockIdx.x * 256 + threadIdx.x;  // 1048576 float4
  float4 a = Hp[gid];
  float4 b = Hp[gid + 1048576];
  float4 c = Hp[gid + 2097152];
  float4 d = Hp[gid + 3145728];
  float4 r;
  r.x = a.x + b.x + c.x + d.x;
  r.y = a.y + b.y + c.y + d.y;
  r.z = a.z + b.z + c.z + d.z;
  r.w = a.w + b.w + c.w + d.w;
  H[gid] = r;
  float s = r.x + r.y + r.z + r.w;
  float ss = r.x * r.x + r.y * r.y + r.z * r.z + r.w * r.w;
  for (int off = 32; off; off >>= 1) {
    s += __shfl_down(s, off);
    ss += __shfl_down(ss, off);
  }
  if ((threadIdx.x & 63) == 0) {
    unsafeAtomicAdd(&stats[0], s);
    unsafeAtomicAdd(&stats[1], ss);
  }
}

// ---------- kernel 5: GroupNorm normalize + bf16 cast ----------
__global__ void norm_kernel(const float4* __restrict__ H, const float* __restrict__ stats,
                            const float* __restrict__ gnw, const float* __restrict__ gnb,
                            ushort4* __restrict__ hnb) {
  const int gid = blockIdx.x * 256 + threadIdx.x;  // 1048576 float4
  const float inv_n = 1.f / (float)N_ELEM;
  const float mean = stats[0] * inv_n;
  const float var = stats[1] * inv_n - mean * mean;
  const float rstd = rsqrtf(var + 1e-5f);
  float4 h = H[gid];
  const int c0 = (gid * 4) & 511;
  const float4 w = *(const float4*)&gnw[c0];
  const float4 b = *(const float4*)&gnb[c0];
  ushort4 o;
  o.x = f2b((h.x - mean) * rstd * w.x + b.x);
  o.y = f2b((h.y - mean) * rstd * w.y + b.y);
  o.z = f2b((h.z - mean) * rstd * w.z + b.z);
  o.w = f2b((h.w - mean) * rstd * w.w + b.w);
  hnb[gid] = o;
}

// ---------- kernel 6: output projection + PReLU ----------
__global__ void gemm_out(const ushort_t* __restrict__ hnb, const ushort_t* __restrict__ wrb,
                         const float* __restrict__ br, const float* __restrict__ prelu,
                         float* __restrict__ out) {
  __shared__ ushort_t As[4 * 130 * 8];
  __shared__ ushort_t Bs[4 * 130 * 8];
  const int tid = threadIdx.x, wid = tid >> 6, lane = tid & 63;
  const int l15 = lane & 15, q4 = lane >> 4;
  const int m0 = blockIdx.x * 128, n0 = blockIdx.y * 128;
  const int m0w = (wid >> 1) * 64, n0w = (wid & 1) * 64;

  f32x4 acc[4][4];
#pragma unroll
  for (int a = 0; a < 4; ++a)
#pragma unroll
    for (int b = 0; b < 4; ++b) acc[a][b] = f32x4{0.f, 0.f, 0.f, 0.f};

  for (int kt = 0; kt < 16; ++kt) {
#pragma unroll
    for (int j = 0; j < 4; ++j) {
      const int idx = wid * 4 + j;
      const int kg = (idx >> 1) & 3;
      const int half = idx & 1;
      if (idx < 8)
        g2l16(&hnb[(size_t)(m0 + half * 64 + lane) * 512 + kt * 32 + kg * 8],
              &As[(kg * 130 + half * 64) * 8]);
      else
        g2l16(&wrb[(size_t)(n0 + half * 64 + lane) * 512 + kt * 32 + kg * 8],
              &Bs[(kg * 130 + half * 64) * 8]);
    }
    __syncthreads();
    bf16x8 af[4], bfr[4];
#pragma unroll
    for (int t = 0; t < 4; ++t) {
      af[t]  = *(const bf16x8*)&As[(q4 * 130 + m0w + t * 16 + l15) * 8];
      bfr[t] = *(const bf16x8*)&Bs[(q4 * 130 + n0w + t * 16 + l15) * 8];
    }
#pragma unroll
    for (int mt = 0; mt < 4; ++mt)
#pragma unroll
      for (int nt = 0; nt < 4; ++nt)
        acc[mt][nt] = __builtin_amdgcn_mfma_f32_16x16x32_bf16(af[mt], bfr[nt], acc[mt][nt], 0, 0, 0);
    __syncthreads();
  }

  const float slope = prelu[0];
#pragma unroll
  for (int nt = 0; nt < 4; ++nt) {
    const int gcol = n0 + n0w + nt * 16 + l15;
    const float bb = br[gcol];
#pragma unroll
    for (int mt = 0; mt < 4; ++mt)
#pragma unroll
      for (int i = 0; i < 4; ++i) {
        const int grow = m0 + m0w + mt * 16 + q4 * 4 + i;
        float v = acc[mt][nt][i] + bb;
        v = (v >= 0.f) ? v : v * slope;
        out[(size_t)grow * 512 + gcol] = v;
      }
  }
}

// ---------- workspace layout (bytes), with aliasing ----------
// xb [0, 16MB) dead after gemm_qkv -> H reused there (stats..gemm_out: disjoint in time)
// Qp [20447232, +8MB) dead after gemm_s -> hnb reused there (norm..gemm_out)
#define OFF_XB  0ULL            // 16777216 (later: H)
#define OFF_H   0ULL
#define OFF_WQB 16777216ULL     // 1048576
#define OFF_WKB 17825792ULL
#define OFF_WVB 18874368ULL
#define OFF_WRB 19922944ULL     // 524288 (live until gemm_out)
#define OFF_QP  20447232ULL     // 8388608 (later: hnb)
#define OFF_HNB 20447232ULL
#define OFF_KP  28835840ULL     // 8388608
#define OFF_VP  37224448ULL     // 8388608
#define OFF_P   45613056ULL     // 134217728
#define OFF_HP  179830784ULL    // 67108864
#define OFF_ST  246939648ULL    // small
// total ~247 MB

extern "C" void kernel_launch(void* const* d_in, const int* in_sizes, int n_in,
                              void* d_out, int out_size, void* d_ws, size_t ws_size,
                              hipStream_t stream) {
  const float* x     = (const float*)d_in[0];
  const float* dg    = (const float*)d_in[1];
  const float* Wq    = (const float*)d_in[2];
  const float* bq    = (const float*)d_in[3];
  const float* Wk    = (const float*)d_in[4];
  const float* bk    = (const float*)d_in[5];
  const float* Wv    = (const float*)d_in[6];
  const float* bv    = (const float*)d_in[7];
  const float* Wr    = (const float*)d_in[8];
  const float* br    = (const float*)d_in[9];
  const float* gnw   = (const float*)d_in[10];
  const float* gnb   = (const float*)d_in[11];
  const float* prelu = (const float*)d_in[12];
  float* out = (float*)d_out;
  char* ws = (char*)d_ws;

  ushort_t* xb  = (ushort_t*)(ws + OFF_XB);
  ushort_t* wqb = (ushort_t*)(ws + OFF_WQB);
  ushort_t* wkb = (ushort_t*)(ws + OFF_WKB);
  ushort_t* wvb = (ushort_t*)(ws + OFF_WVB);
  ushort_t* wrb = (ushort_t*)(ws + OFF_WRB);
  ushort_t* Qp  = (ushort_t*)(ws + OFF_QP);
  ushort_t* Kp  = (ushort_t*)(ws + OFF_KP);
  ushort_t* Vp  = (ushort_t*)(ws + OFF_VP);
  ushort_t* P   = (ushort_t*)(ws + OFF_P);
  float* Hp     = (float*)(ws + OFF_HP);
  float* H      = (float*)(ws + OFF_H);
  ushort_t* hnb = (ushort_t*)(ws + OFF_HNB);
  float* stats  = (float*)(ws + OFF_ST);

  prep_kernel<<<9984, 256, 0, stream>>>(
      (const float4*)x, (const float4*)Wq, (const float4*)Wk, (const float4*)Wv,
      (const float4*)Wr, (ushort4*)xb, (ushort4*)wqb, (ushort4*)wkb, (ushort4*)wvb,
      (ushort4*)wrb, stats);

  gemm_qkv<<<dim3(64, 4, 3), 256, 0, stream>>>(xb, wqb, wkb, wvb, bq, bk, bv, Qp, Kp, Vp);

  gemm_s<<<dim3(64, 64), 256, 0, stream>>>(Qp, Kp, dg, P);

  gemm_pv<<<dim3(64, 4, 4), 256, 0, stream>>>(P, Vp, Hp);

  stats_kernel<<<4096, 256, 0, stream>>>((const float4*)Hp, (float4*)H, stats);

  norm_kernel<<<4096, 256, 0, stream>>>((const float4*)H, stats, gnw, gnb, (ushort4*)hnb);

  gemm_out<<<dim3(64, 4), 256, 0, stream>>>(hnb, wrb, br, prelu, out);
}

// Round 4
// 709.704 us; speedup vs baseline: 1.5703x; 1.5703x over previous
//
#include <hip/hip_runtime.h>

typedef unsigned short ushort_t;
typedef unsigned int u32;
typedef __attribute__((ext_vector_type(4))) float f32x4;
typedef __attribute__((ext_vector_type(8))) short bf16x8;

// Problem constants
#define T_DIM 8192
#define D_IN 1024
#define D_INTER 512
#define N_ELEM (T_DIM * D_INTER)  // 4194304

// ---------- helpers ----------
__device__ __forceinline__ unsigned short f2b(float f) {
  union { float f; u32 u; } v; v.f = f;
  u32 u = v.u;
  u32 r = (u + 0x7fffu + ((u >> 16) & 1u)) >> 16;
  return (unsigned short)r;
}

__device__ __forceinline__ void g2l16(const void* g, void* l) {
  __builtin_amdgcn_global_load_lds((const __attribute__((address_space(1))) u32*)g,
                                   (__attribute__((address_space(3))) u32*)l, 16, 0, 0);
}

// ---------- kernel 1: casts ----------
// segments (float4 units): x 2097152 | wq 131072 | wk 131072 | wv 131072 | wr 65536
__global__ void prep_kernel(const float4* __restrict__ x,
                            const float4* __restrict__ wq, const float4* __restrict__ wk,
                            const float4* __restrict__ wv, const float4* __restrict__ wr,
                            ushort4* __restrict__ xb,
                            ushort4* __restrict__ wqb, ushort4* __restrict__ wkb,
                            ushort4* __restrict__ wvb, ushort4* __restrict__ wrb) {
  const int gid = blockIdx.x * 256 + threadIdx.x;
  const float4* src; ushort4* dst; int idx;
  if (gid < 2097152)      { src = x;  dst = xb;  idx = gid; }
  else if (gid < 2228224) { src = wq; dst = wqb; idx = gid - 2097152; }
  else if (gid < 2359296) { src = wk; dst = wkb; idx = gid - 2228224; }
  else if (gid < 2490368) { src = wv; dst = wvb; idx = gid - 2359296; }
  else                    { src = wr; dst = wrb; idx = gid - 2490368; }
  float4 v = src[idx];
  ushort4 o;
  o.x = f2b(v.x); o.y = f2b(v.y); o.z = f2b(v.z); o.w = f2b(v.w);
  dst[idx] = o;
}

// ---------- kernel 2: QKV projections  C = xb @ W^T + b ----------
// M=8192, K=1024, N=512, blockIdx.z in {0:Q,1:K,2:V}. 128x128 tiles, BK=32.
// Q,K outputs k-packed over inter (cell(kg,row)); V k-packed over T (cell(tg,col)).
__global__ void gemm_qkv(const ushort_t* __restrict__ xb,
                         const ushort_t* __restrict__ wqb, const ushort_t* __restrict__ wkb,
                         const ushort_t* __restrict__ wvb,
                         const float* __restrict__ bq, const float* __restrict__ bk,
                         const float* __restrict__ bv,
                         ushort_t* __restrict__ Qp, ushort_t* __restrict__ Kp,
                         ushort_t* __restrict__ Vp) {
  __shared__ ushort_t As[4 * 130 * 8];
  __shared__ ushort_t Bs[4 * 130 * 8];
  const int tid = threadIdx.x, wid = tid >> 6, lane = tid & 63;
  const int l15 = lane & 15, q4 = lane >> 4;
  const int m0 = blockIdx.x * 128, n0 = blockIdx.y * 128;
  const int z = blockIdx.z;
  const ushort_t* wb = (z == 0) ? wqb : (z == 1 ? wkb : wvb);
  const float* bias = (z == 0) ? bq : (z == 1 ? bk : bv);
  const int m0w = (wid >> 1) * 64, n0w = (wid & 1) * 64;

  f32x4 acc[4][4];
#pragma unroll
  for (int a = 0; a < 4; ++a)
#pragma unroll
    for (int b = 0; b < 4; ++b) acc[a][b] = f32x4{0.f, 0.f, 0.f, 0.f};

  for (int kt = 0; kt < 32; ++kt) {
#pragma unroll
    for (int j = 0; j < 4; ++j) {
      const int idx = wid * 4 + j;
      const int kg = (idx >> 1) & 3;
      const int half = idx & 1;
      if (idx < 8)
        g2l16(&xb[(size_t)(m0 + half * 64 + lane) * 1024 + kt * 32 + kg * 8],
              &As[(kg * 130 + half * 64) * 8]);
      else
        g2l16(&wb[(size_t)(n0 + half * 64 + lane) * 1024 + kt * 32 + kg * 8],
              &Bs[(kg * 130 + half * 64) * 8]);
    }
    __syncthreads();
    bf16x8 af[4], bfr[4];
#pragma unroll
    for (int t = 0; t < 4; ++t) {
      af[t]  = *(const bf16x8*)&As[(q4 * 130 + m0w + t * 16 + l15) * 8];
      bfr[t] = *(const bf16x8*)&Bs[(q4 * 130 + n0w + t * 16 + l15) * 8];
    }
#pragma unroll
    for (int mt = 0; mt < 4; ++mt)
#pragma unroll
      for (int nt = 0; nt < 4; ++nt)
        acc[mt][nt] = __builtin_amdgcn_mfma_f32_16x16x32_bf16(af[mt], bfr[nt], acc[mt][nt], 0, 0, 0);
    __syncthreads();
  }

#pragma unroll
  for (int nt = 0; nt < 4; ++nt) {
    const int gcol = n0 + n0w + nt * 16 + l15;
    const float bb = bias[gcol];
#pragma unroll
    for (int mt = 0; mt < 4; ++mt)
#pragma unroll
      for (int i = 0; i < 4; ++i) {
        const int grow = m0 + m0w + mt * 16 + q4 * 4 + i;
        const unsigned short v = f2b(acc[mt][nt][i] + bb);
        if (z == 2)
          Vp[((size_t)(grow >> 3) * 512 + gcol) * 8 + (grow & 7)] = v;   // k = T rows
        else if (z == 1)
          Kp[((size_t)(gcol >> 3) * 8192 + grow) * 8 + (gcol & 7)] = v;  // k = inter
        else
          Qp[((size_t)(gcol >> 3) * 8192 + grow) * 8 + (gcol & 7)] = v;
      }
  }
}

// ---------- kernel 3a: P = dg o (Q K^T) -> bf16, row-major [8192 x 8192] ----------
// M=N=8192, K=512. Grid (64,64), 256 threads. m97 structure; dg applied in epilogue.
__global__ void gemm_s(const ushort_t* __restrict__ Qp, const ushort_t* __restrict__ Kp,
                       const float* __restrict__ dg, ushort_t* __restrict__ P) {
  __shared__ ushort_t As[4 * 130 * 8];
  __shared__ ushort_t Bs[4 * 130 * 8];
  const int tid = threadIdx.x, wid = tid >> 6, lane = tid & 63;
  const int l15 = lane & 15, q4 = lane >> 4;
  const int m0 = blockIdx.x * 128, n0 = blockIdx.y * 128;
  const int m0w = (wid >> 1) * 64, n0w = (wid & 1) * 64;

  f32x4 acc[4][4];
#pragma unroll
  for (int a = 0; a < 4; ++a)
#pragma unroll
    for (int b = 0; b < 4; ++b) acc[a][b] = f32x4{0.f, 0.f, 0.f, 0.f};

  for (int kt = 0; kt < 16; ++kt) {
#pragma unroll
    for (int j = 0; j < 4; ++j) {
      const int idx = wid * 4 + j;
      const int kg = (idx >> 1) & 3;
      const int half = idx & 1;
      if (idx < 8)
        g2l16(&Qp[((size_t)(kt * 4 + kg) * 8192 + m0 + half * 64 + lane) * 8],
              &As[(kg * 130 + half * 64) * 8]);
      else
        g2l16(&Kp[((size_t)(kt * 4 + kg) * 8192 + n0 + half * 64 + lane) * 8],
              &Bs[(kg * 130 + half * 64) * 8]);
    }
    __syncthreads();
    bf16x8 af[4], bfr[4];
#pragma unroll
    for (int t = 0; t < 4; ++t) {
      af[t]  = *(const bf16x8*)&As[(q4 * 130 + m0w + t * 16 + l15) * 8];
      bfr[t] = *(const bf16x8*)&Bs[(q4 * 130 + n0w + t * 16 + l15) * 8];
    }
#pragma unroll
    for (int mt = 0; mt < 4; ++mt)
#pragma unroll
      for (int nt = 0; nt < 4; ++nt)
        acc[mt][nt] = __builtin_amdgcn_mfma_f32_16x16x32_bf16(af[mt], bfr[nt], acc[mt][nt], 0, 0, 0);
    __syncthreads();
  }

  // epilogue: P[grow][gcol] = bf16( dg[grow][gcol] * acc )
#pragma unroll
  for (int mt = 0; mt < 4; ++mt)
#pragma unroll
    for (int i = 0; i < 4; ++i) {
      const size_t grow = (size_t)(m0 + m0w + mt * 16 + q4 * 4 + i);
#pragma unroll
      for (int nt = 0; nt < 4; ++nt) {
        const int gcol = n0 + n0w + nt * 16 + l15;
        const float g = dg[grow * 8192 + gcol];
        P[grow * 8192 + gcol] = f2b(acc[mt][nt][i] * g);
      }
    }
}

// ---------- kernel 3b: Hp[z] = P @ V  (split-K=4) ----------
// M=8192, N=512, K=8192 split into 4 chunks of 2048. Grid (64,4,4), 256 threads.
__global__ void gemm_pv(const ushort_t* __restrict__ P, const ushort_t* __restrict__ Vp,
                        float* __restrict__ Hp) {
  __shared__ ushort_t As[4 * 130 * 8];
  __shared__ ushort_t Bs[4 * 130 * 8];
  const int tid = threadIdx.x, wid = tid >> 6, lane = tid & 63;
  const int l15 = lane & 15, q4 = lane >> 4;
  const int m0 = blockIdx.x * 128, n0 = blockIdx.y * 128;
  const int kz = blockIdx.z;
  const int tg_base = kz * 256;  // k-chunk start in tg units (2048/8)
  const int m0w = (wid >> 1) * 64, n0w = (wid & 1) * 64;

  f32x4 acc[4][4];
#pragma unroll
  for (int a = 0; a < 4; ++a)
#pragma unroll
    for (int b = 0; b < 4; ++b) acc[a][b] = f32x4{0.f, 0.f, 0.f, 0.f};

  for (int kt = 0; kt < 64; ++kt) {
    const int kk = kz * 2048 + kt * 32;
#pragma unroll
    for (int j = 0; j < 4; ++j) {
      const int idx = wid * 4 + j;
      const int kg = (idx >> 1) & 3;
      const int half = idx & 1;
      if (idx < 8)
        g2l16(&P[(size_t)(m0 + half * 64 + lane) * 8192 + kk + kg * 8],
              &As[(kg * 130 + half * 64) * 8]);
      else
        g2l16(&Vp[((size_t)(tg_base + kt * 4 + kg) * 512 + n0 + half * 64 + lane) * 8],
              &Bs[(kg * 130 + half * 64) * 8]);
    }
    __syncthreads();
    bf16x8 af[4], bfr[4];
#pragma unroll
    for (int t = 0; t < 4; ++t) {
      af[t]  = *(const bf16x8*)&As[(q4 * 130 + m0w + t * 16 + l15) * 8];
      bfr[t] = *(const bf16x8*)&Bs[(q4 * 130 + n0w + t * 16 + l15) * 8];
    }
#pragma unroll
    for (int mt = 0; mt < 4; ++mt)
#pragma unroll
      for (int nt = 0; nt < 4; ++nt)
        acc[mt][nt] = __builtin_amdgcn_mfma_f32_16x16x32_bf16(af[mt], bfr[nt], acc[mt][nt], 0, 0, 0);
    __syncthreads();
  }

  float* hp = Hp + (size_t)kz * N_ELEM;
#pragma unroll
  for (int mt = 0; mt < 4; ++mt)
#pragma unroll
    for (int i = 0; i < 4; ++i) {
      const size_t grow = (size_t)(m0 + m0w + mt * 16 + q4 * 4 + i);
#pragma unroll
      for (int nt = 0; nt < 4; ++nt) {
        const int gcol = n0 + n0w + nt * 16 + l15;
        hp[grow * 512 + gcol] = acc[mt][nt][i];
      }
    }
}

// ---------- kernel 4: reduce split-K partials + per-block (sum, sumsq) partials ----------
// NO global atomics: per-block LDS reduce -> one float2 store per block.
__global__ void stats_kernel(const float4* __restrict__ Hp, float4* __restrict__ H,
                             float2* __restrict__ partials) {
  __shared__ float2 wsum[4];
  const int gid = blockIdx.x * 256 + threadIdx.x;  // 1048576 float4
  float4 a = Hp[gid];
  float4 b = Hp[gid + 1048576];
  float4 c = Hp[gid + 2097152];
  float4 d = Hp[gid + 3145728];
  float4 r;
  r.x = a.x + b.x + c.x + d.x;
  r.y = a.y + b.y + c.y + d.y;
  r.z = a.z + b.z + c.z + d.z;
  r.w = a.w + b.w + c.w + d.w;
  H[gid] = r;
  float s = r.x + r.y + r.z + r.w;
  float ss = r.x * r.x + r.y * r.y + r.z * r.z + r.w * r.w;
  for (int off = 32; off; off >>= 1) {
    s += __shfl_down(s, off);
    ss += __shfl_down(ss, off);
  }
  const int wid = threadIdx.x >> 6;
  if ((threadIdx.x & 63) == 0) wsum[wid] = make_float2(s, ss);
  __syncthreads();
  if (threadIdx.x == 0) {
    float2 t0 = wsum[0], t1 = wsum[1], t2 = wsum[2], t3 = wsum[3];
    partials[blockIdx.x] = make_float2(t0.x + t1.x + t2.x + t3.x,
                                       t0.y + t1.y + t2.y + t3.y);
  }
}

// ---------- kernel 4b: final reduction of 4096 block partials ----------
__global__ void stats2_kernel(const float2* __restrict__ partials, float* __restrict__ stats) {
  __shared__ float2 wsum[16];
  float s = 0.f, ss = 0.f;
#pragma unroll
  for (int i = 0; i < 4; ++i) {
    float2 p = partials[threadIdx.x + i * 1024];
    s += p.x; ss += p.y;
  }
  for (int off = 32; off; off >>= 1) {
    s += __shfl_down(s, off);
    ss += __shfl_down(ss, off);
  }
  const int wid = threadIdx.x >> 6;
  if ((threadIdx.x & 63) == 0) wsum[wid] = make_float2(s, ss);
  __syncthreads();
  if (threadIdx.x == 0) {
    float fs = 0.f, fss = 0.f;
#pragma unroll
    for (int i = 0; i < 16; ++i) { fs += wsum[i].x; fss += wsum[i].y; }
    stats[0] = fs;
    stats[1] = fss;
  }
}

// ---------- kernel 5: GroupNorm normalize + bf16 cast ----------
__global__ void norm_kernel(const float4* __restrict__ H, const float* __restrict__ stats,
                            const float* __restrict__ gnw, const float* __restrict__ gnb,
                            ushort4* __restrict__ hnb) {
  const int gid = blockIdx.x * 256 + threadIdx.x;  // 1048576 float4
  const float inv_n = 1.f / (float)N_ELEM;
  const float mean = stats[0] * inv_n;
  const float var = stats[1] * inv_n - mean * mean;
  const float rstd = rsqrtf(var + 1e-5f);
  float4 h = H[gid];
  const int c0 = (gid * 4) & 511;
  const float4 w = *(const float4*)&gnw[c0];
  const float4 b = *(const float4*)&gnb[c0];
  ushort4 o;
  o.x = f2b((h.x - mean) * rstd * w.x + b.x);
  o.y = f2b((h.y - mean) * rstd * w.y + b.y);
  o.z = f2b((h.z - mean) * rstd * w.z + b.z);
  o.w = f2b((h.w - mean) * rstd * w.w + b.w);
  hnb[gid] = o;
}

// ---------- kernel 6: output projection + PReLU ----------
__global__ void gemm_out(const ushort_t* __restrict__ hnb, const ushort_t* __restrict__ wrb,
                         const float* __restrict__ br, const float* __restrict__ prelu,
                         float* __restrict__ out) {
  __shared__ ushort_t As[4 * 130 * 8];
  __shared__ ushort_t Bs[4 * 130 * 8];
  const int tid = threadIdx.x, wid = tid >> 6, lane = tid & 63;
  const int l15 = lane & 15, q4 = lane >> 4;
  const int m0 = blockIdx.x * 128, n0 = blockIdx.y * 128;
  const int m0w = (wid >> 1) * 64, n0w = (wid & 1) * 64;

  f32x4 acc[4][4];
#pragma unroll
  for (int a = 0; a < 4; ++a)
#pragma unroll
    for (int b = 0; b < 4; ++b) acc[a][b] = f32x4{0.f, 0.f, 0.f, 0.f};

  for (int kt = 0; kt < 16; ++kt) {
#pragma unroll
    for (int j = 0; j < 4; ++j) {
      const int idx = wid * 4 + j;
      const int kg = (idx >> 1) & 3;
      const int half = idx & 1;
      if (idx < 8)
        g2l16(&hnb[(size_t)(m0 + half * 64 + lane) * 512 + kt * 32 + kg * 8],
              &As[(kg * 130 + half * 64) * 8]);
      else
        g2l16(&wrb[(size_t)(n0 + half * 64 + lane) * 512 + kt * 32 + kg * 8],
              &Bs[(kg * 130 + half * 64) * 8]);
    }
    __syncthreads();
    bf16x8 af[4], bfr[4];
#pragma unroll
    for (int t = 0; t < 4; ++t) {
      af[t]  = *(const bf16x8*)&As[(q4 * 130 + m0w + t * 16 + l15) * 8];
      bfr[t] = *(const bf16x8*)&Bs[(q4 * 130 + n0w + t * 16 + l15) * 8];
    }
#pragma unroll
    for (int mt = 0; mt < 4; ++mt)
#pragma unroll
      for (int nt = 0; nt < 4; ++nt)
        acc[mt][nt] = __builtin_amdgcn_mfma_f32_16x16x32_bf16(af[mt], bfr[nt], acc[mt][nt], 0, 0, 0);
    __syncthreads();
  }

  const float slope = prelu[0];
#pragma unroll
  for (int nt = 0; nt < 4; ++nt) {
    const int gcol = n0 + n0w + nt * 16 + l15;
    const float bb = br[gcol];
#pragma unroll
    for (int mt = 0; mt < 4; ++mt)
#pragma unroll
      for (int i = 0; i < 4; ++i) {
        const int grow = m0 + m0w + mt * 16 + q4 * 4 + i;
        float v = acc[mt][nt][i] + bb;
        v = (v >= 0.f) ? v : v * slope;
        out[(size_t)grow * 512 + gcol] = v;
      }
  }
}

// ---------- workspace layout (bytes), with aliasing ----------
// xb [0, 16MB) dead after gemm_qkv -> H reused there
// Qp [20447232, +8MB) dead after gemm_s -> hnb reused there
#define OFF_XB   0ULL            // 16777216 (later: H)
#define OFF_H    0ULL
#define OFF_WQB  16777216ULL     // 1048576
#define OFF_WKB  17825792ULL
#define OFF_WVB  18874368ULL
#define OFF_WRB  19922944ULL     // 524288 (live until gemm_out)
#define OFF_QP   20447232ULL     // 8388608 (later: hnb)
#define OFF_HNB  20447232ULL
#define OFF_KP   28835840ULL     // 8388608
#define OFF_VP   37224448ULL     // 8388608
#define OFF_P    45613056ULL     // 134217728
#define OFF_HP   179830784ULL    // 67108864
#define OFF_ST   246939648ULL    // 512
#define OFF_PART 246940160ULL    // 32768 (4096 float2)
// total ~247 MB

extern "C" void kernel_launch(void* const* d_in, const int* in_sizes, int n_in,
                              void* d_out, int out_size, void* d_ws, size_t ws_size,
                              hipStream_t stream) {
  const float* x     = (const float*)d_in[0];
  const float* dg    = (const float*)d_in[1];
  const float* Wq    = (const float*)d_in[2];
  const float* bq    = (const float*)d_in[3];
  const float* Wk    = (const float*)d_in[4];
  const float* bk    = (const float*)d_in[5];
  const float* Wv    = (const float*)d_in[6];
  const float* bv    = (const float*)d_in[7];
  const float* Wr    = (const float*)d_in[8];
  const float* br    = (const float*)d_in[9];
  const float* gnw   = (const float*)d_in[10];
  const float* gnb   = (const float*)d_in[11];
  const float* prelu = (const float*)d_in[12];
  float* out = (float*)d_out;
  char* ws = (char*)d_ws;

  ushort_t* xb  = (ushort_t*)(ws + OFF_XB);
  ushort_t* wqb = (ushort_t*)(ws + OFF_WQB);
  ushort_t* wkb = (ushort_t*)(ws + OFF_WKB);
  ushort_t* wvb = (ushort_t*)(ws + OFF_WVB);
  ushort_t* wrb = (ushort_t*)(ws + OFF_WRB);
  ushort_t* Qp  = (ushort_t*)(ws + OFF_QP);
  ushort_t* Kp  = (ushort_t*)(ws + OFF_KP);
  ushort_t* Vp  = (ushort_t*)(ws + OFF_VP);
  ushort_t* P   = (ushort_t*)(ws + OFF_P);
  float* Hp     = (float*)(ws + OFF_HP);
  float* H      = (float*)(ws + OFF_H);
  ushort_t* hnb = (ushort_t*)(ws + OFF_HNB);
  float* stats  = (float*)(ws + OFF_ST);
  float2* part  = (float2*)(ws + OFF_PART);

  prep_kernel<<<9984, 256, 0, stream>>>(
      (const float4*)x, (const float4*)Wq, (const float4*)Wk, (const float4*)Wv,
      (const float4*)Wr, (ushort4*)xb, (ushort4*)wqb, (ushort4*)wkb, (ushort4*)wvb,
      (ushort4*)wrb);

  gemm_qkv<<<dim3(64, 4, 3), 256, 0, stream>>>(xb, wqb, wkb, wvb, bq, bk, bv, Qp, Kp, Vp);

  gemm_s<<<dim3(64, 64), 256, 0, stream>>>(Qp, Kp, dg, P);

  gemm_pv<<<dim3(64, 4, 4), 256, 0, stream>>>(P, Vp, Hp);

  stats_kernel<<<4096, 256, 0, stream>>>((const float4*)Hp, (float4*)H, part);

  stats2_kernel<<<1, 1024, 0, stream>>>(part, stats);

  norm_kernel<<<4096, 256, 0, stream>>>((const float4*)H, stats, gnw, gnb, (ushort4*)hnb);

  gemm_out<<<dim3(64, 4), 256, 0, stream>>>(hnb, wrb, br, prelu, out);
}